// Round 4
// baseline (1247.952 us; speedup 1.0000x reference)
//
// R3: resubmission of R2 (bench never ran - GPU acquisition timeout).
// Experiment under test: wave-aggregated radix histograms (wave_hist_add)
// to kill the 3.0M-cycle LDS same-address atomic serialization in k_top/k_select.
#include <hip/hip_runtime.h>
#include <cstdint>
#include <cstddef>

#define NCLS   80
#define NB     16
#define NPTS   21824      // 16384+4096+1024+256+64
#define NSEL   3320       // 1000+1000+1000+256+64
#define NCAND  2000
#define MAXPER 100

__device__ __forceinline__ float sigmoidf_(float x){ return 1.0f/(1.0f+expf(-x)); }
// monotone-increasing unsigned key for f32 (finite inputs)
__device__ __forceinline__ unsigned fkey(float f){
    unsigned u = __float_as_uint(f);
    return (u & 0x80000000u) ? ~u : (u | 0x80000000u);
}

// wave-aggregated histogram add: one LDS atomic per distinct bucket per wave
// (keys are heavily clustered -> naive per-lane atomics serialize 64-way)
__device__ __forceinline__ void wave_hist_add(unsigned* hist, int bucket, bool active){
    unsigned long long rem = __ballot(active);
    int lane = threadIdx.x & 63;
    while (rem){
        int leader = __ffsll((long long)rem) - 1;
        int lb = __shfl(bucket, leader);
        unsigned long long match = __ballot(active && bucket == lb);
        if (lane == leader) atomicAdd(&hist[lb], (unsigned)__popcll(match));
        rem &= ~match;
    }
}

// ---------------- K1: per-point max class score (sigmoid of max logit), float4 ----------------
__global__ void k_maxscore(const float* __restrict__ c0, const float* __restrict__ c1,
                           const float* __restrict__ c2, const float* __restrict__ c3,
                           const float* __restrict__ c4, float* __restrict__ maxscore){
    const int GP = NPTS/4;                       // 5456 point-groups per image
    int g = blockIdx.x*blockDim.x + threadIdx.x;
    if (g >= NB*GP) return;
    int b = g / GP, r = (g - b*GP)*4;            // r = first point of the 4-group
    const float* cls; int n, p;
    if      (r < 16384){ cls=c0; n=16384; p=r; }
    else if (r < 20480){ cls=c1; n=4096;  p=r-16384; }
    else if (r < 21504){ cls=c2; n=1024;  p=r-20480; }
    else if (r < 21760){ cls=c3; n=256;   p=r-21504; }
    else               { cls=c4; n=64;    p=r-21760; }
    const float* base = cls + (size_t)b*NCLS*n + p;
    float4 m = make_float4(-3.4e38f,-3.4e38f,-3.4e38f,-3.4e38f);
    #pragma unroll 8
    for (int c = 0; c < NCLS; ++c){
        const float4 v = *(const float4*)(base + (size_t)c*n);
        m.x = fmaxf(m.x, v.x); m.y = fmaxf(m.y, v.y);
        m.z = fmaxf(m.z, v.z); m.w = fmaxf(m.w, v.w);
    }
    float4 s = make_float4(sigmoidf_(m.x), sigmoidf_(m.y), sigmoidf_(m.z), sigmoidf_(m.w));
    *(float4*)(maxscore + (size_t)b*NPTS + r) = s;
}

// ---------------- K2: per-(image,level) top-k point selection (radix select) ----------------
__global__ void k_select(const float* __restrict__ maxscore, int* __restrict__ sel){
    int blk = blockIdx.x; int b = blk/5, li = blk - 5*b;
    int n, k, poff, soff;
    if      (li==0){ n=16384; k=1000; poff=0;     soff=0;    }
    else if (li==1){ n=4096;  k=1000; poff=16384; soff=1000; }
    else if (li==2){ n=1024;  k=1000; poff=20480; soff=2000; }
    else if (li==3){ n=256;   k=256;  poff=21504; soff=3000; }
    else           { n=64;    k=64;   poff=21760; soff=3256; }
    const float* x = maxscore + b*NPTS + poff;
    int* out = sel + b*NSEL + soff;
    int tid = threadIdx.x, nt = blockDim.x;
    if (k == n){ for (int i=tid;i<n;i+=nt) out[i]=i; return; }

    __shared__ unsigned hist[256];
    __shared__ unsigned sh_pref; __shared__ int sh_rem;
    unsigned prefix = 0; int rem = k;
    for (int pass = 0; pass < 4; ++pass){
        int shift = 24 - 8*pass;
        for (int i=tid;i<256;i+=nt) hist[i]=0u;
        __syncthreads();
        for (int i0=0; i0<n; i0+=nt){
            int i = i0 + tid;
            bool act = false; int bucket = 0;
            if (i < n){
                unsigned key = fkey(x[i]);
                act = (pass==0 || (key >> (shift+8)) == prefix);
                bucket = (int)((key>>shift)&255u);
            }
            wave_hist_add(hist, bucket, act);
        }
        __syncthreads();
        if (tid==0){
            unsigned cum=0; int d=255;
            for(;;){ unsigned cc=hist[d]; if (cum+cc >= (unsigned)rem || d==0) break; cum+=cc; --d; }
            sh_pref = (prefix<<8) | (unsigned)d; sh_rem = rem - (int)cum;
        }
        __syncthreads();
        prefix = sh_pref; rem = sh_rem;
        __syncthreads();
    }
    unsigned T = prefix; int r = rem; int base = k - r;
    __shared__ int sh_cnt, sh_tc, sh_tp;
    if (tid==0){ sh_cnt=0; sh_tc=0; sh_tp=0; }
    __syncthreads();
    for (int i=tid;i<n;i+=nt){
        unsigned key = fkey(x[i]);
        if (key > T){ out[atomicAdd(&sh_cnt,1)] = i; }
        else if (key == T){ atomicAdd(&sh_tc,1); }
    }
    __syncthreads();
    int tc = sh_tc;
    if (tc == r){
        // exact tied set: order within output irrelevant (set semantics downstream)
        for (int i=tid;i<n;i+=nt)
            if (fkey(x[i]) == T) out[base + atomicAdd(&sh_tp,1)] = i;
    } else {
        // rare: pick the r lowest-indexed tied elements (matches lax.top_k)
        __shared__ int running; __shared__ int wt[4];
        if (tid==0) running = 0;
        __syncthreads();
        int lane = tid & 63, wid = tid >> 6, nw = nt >> 6;
        for (int i0=0; i0<n; i0+=nt){
            int i = i0 + tid;
            bool f = (i < n) && (fkey(x[i]) == T);
            unsigned long long m = __ballot(f);
            if (lane==0) wt[wid] = __popcll(m);
            __syncthreads();
            int wb = 0; for (int w=0;w<wid;++w) wb += wt[w];
            int rank = running + wb + __popcll(m & ((1ull<<lane)-1ull));
            if (f && rank < r) out[base+rank] = i;
            __syncthreads();
            if (tid==0){ int tot=0; for (int w=0;w<nw;++w) tot += wt[w]; running += tot; }
            __syncthreads();
        }
    }
}

// ---------------- K3: gather selected points, decode boxes, fused thresholded scores ----------------
__global__ void k_gather(const float* __restrict__ c0, const float* __restrict__ c1,
                         const float* __restrict__ c2, const float* __restrict__ c3,
                         const float* __restrict__ c4,
                         const float* __restrict__ b0, const float* __restrict__ b1,
                         const float* __restrict__ b2, const float* __restrict__ b3,
                         const float* __restrict__ b4,
                         const float* __restrict__ t0, const float* __restrict__ t1,
                         const float* __restrict__ t2, const float* __restrict__ t3,
                         const float* __restrict__ t4,
                         const int* __restrict__ imsz, const int* __restrict__ sel,
                         float* __restrict__ boxes, float* __restrict__ finals){
    size_t i = (size_t)blockIdx.x*blockDim.x + threadIdx.x;
    const size_t total = (size_t)NB*NSEL*NCLS;
    if (i >= total) return;
    int b = (int)(i / (NSEL*NCLS));
    int r = (int)(i - (size_t)b*(NSEL*NCLS));
    int slot = r / NCLS, c = r - slot*NCLS;
    const float *cls, *bb, *ct; int n, hw, st;
    if      (slot < 1000){ cls=c0; bb=b0; ct=t0; n=16384; hw=128; st=8;   }
    else if (slot < 2000){ cls=c1; bb=b1; ct=t1; n=4096;  hw=64;  st=16;  }
    else if (slot < 3000){ cls=c2; bb=b2; ct=t2; n=1024;  hw=32;  st=32;  }
    else if (slot < 3256){ cls=c3; bb=b3; ct=t3; n=256;   hw=16;  st=64;  }
    else                 { cls=c4; bb=b4; ct=t4; n=64;    hw=8;   st=128; }
    int p = sel[b*NSEL + slot];
    float ctrn = sigmoidf_(ct[(size_t)b*n + p]);
    float sc = sigmoidf_(cls[((size_t)b*NCLS + c)*n + p]) * ctrn;
    finals[(size_t)b*NSEL*NCLS + r] = (sc > 0.05f) ? sc : 0.0f;
    if (c == 0){
        const float* base = bb + (size_t)b*4*n;
        float d0 = base[p], d1 = base[n+p], d2 = base[2*n+p], d3 = base[3*n+p];
        int py = p / hw, px = p - py*hw;
        float mx = (float)(px*st + st/2), my = (float)(py*st + st/2);
        float w = (float)imsz[b*2+1], h = (float)imsz[b*2+0];
        float x1 = fminf(fmaxf(mx - d0, 0.0f), w);
        float y1 = fminf(fmaxf(my - d1, 0.0f), h);
        float x2 = fminf(fmaxf(mx + d2, 0.0f), w);
        float y2 = fminf(fmaxf(my + d3, 0.0f), h);
        float* bo = boxes + ((size_t)b*NSEL + slot)*4;
        bo[0]=x1; bo[1]=y1; bo[2]=x2; bo[3]=y2;
    }
}

// ---------------- K4: per-image top-2000 (radix select + compaction) ----------------
__global__ void k_top(const float* __restrict__ finals, const float* __restrict__ boxes,
                      float* __restrict__ cscore, float* __restrict__ cbox,
                      int* __restrict__ clab){
    int b = blockIdx.x;
    const int n = NSEL*NCLS, k = NCAND;
    const float* x = finals + (size_t)b*n;
    int tid = threadIdx.x, nt = blockDim.x;
    __shared__ unsigned hist[256];
    __shared__ unsigned sh_pref; __shared__ int sh_rem;
    unsigned prefix = 0; int rem = k;
    for (int pass = 0; pass < 4; ++pass){
        int shift = 24 - 8*pass;
        for (int i=tid;i<256;i+=nt) hist[i]=0u;
        __syncthreads();
        for (int i0=0; i0<n; i0+=nt){
            int i = i0 + tid;
            bool act = false; int bucket = 0;
            if (i < n){
                unsigned key = fkey(x[i]);
                act = (pass==0 || (key >> (shift+8)) == prefix);
                bucket = (int)((key>>shift)&255u);
            }
            wave_hist_add(hist, bucket, act);
        }
        __syncthreads();
        if (tid==0){
            unsigned cum=0; int d=255;
            for(;;){ unsigned cc=hist[d]; if (cum+cc >= (unsigned)rem || d==0) break; cum+=cc; --d; }
            sh_pref = (prefix<<8) | (unsigned)d; sh_rem = rem - (int)cum;
        }
        __syncthreads();
        prefix = sh_pref; rem = sh_rem;
        __syncthreads();
    }
    unsigned T = prefix; int r = rem; int base = k - r;
    __shared__ int sh_cnt, sh_tc, sh_tp;
    if (tid==0){ sh_cnt=0; sh_tc=0; sh_tp=0; }
    __syncthreads();
    for (int i=tid;i<n;i+=nt){
        unsigned key = fkey(x[i]);
        if (key > T){
            int pos = atomicAdd(&sh_cnt,1);
            int slot = i/NCLS, lab = i - slot*NCLS;
            int ci = b*NCAND + pos;
            cscore[ci] = x[i]; clab[ci] = lab;
            *(float4*)(cbox + (size_t)ci*4) = *(const float4*)(boxes + ((size_t)b*NSEL + slot)*4);
        } else if (key == T){ atomicAdd(&sh_tc,1); }
    }
    __syncthreads();
    int tc = sh_tc;
    if (tc == r){
        for (int i=tid;i<n;i+=nt){
            if (fkey(x[i]) == T){
                int pos = base + atomicAdd(&sh_tp,1);
                int slot = i/NCLS, lab = i - slot*NCLS;
                int ci = b*NCAND + pos;
                cscore[ci] = x[i]; clab[ci] = lab;
                *(float4*)(cbox + (size_t)ci*4) = *(const float4*)(boxes + ((size_t)b*NSEL + slot)*4);
            }
        }
    } else {
        __shared__ int running; __shared__ int wt[16];
        if (tid==0) running = 0;
        __syncthreads();
        int lane = tid & 63, wid = tid >> 6, nw = nt >> 6;
        for (int i0=0; i0<n; i0+=nt){
            int i = i0 + tid;
            bool f = (i < n) && (fkey(x[i]) == T);
            unsigned long long m = __ballot(f);
            if (lane==0) wt[wid] = __popcll(m);
            __syncthreads();
            int wb = 0; for (int w=0;w<wid;++w) wb += wt[w];
            int rank = running + wb + __popcll(m & ((1ull<<lane)-1ull));
            if (f && rank < r){
                int pos = base + rank;
                int slot = i/NCLS, lab = i - slot*NCLS;
                int ci = b*NCAND + pos;
                cscore[ci] = x[i]; clab[ci] = lab;
                *(float4*)(cbox + (size_t)ci*4) = *(const float4*)(boxes + ((size_t)b*NSEL + slot)*4);
            }
            __syncthreads();
            if (tid==0){ int tot=0; for (int w=0;w<nw;++w) tot += wt[w]; running += tot; }
            __syncthreads();
        }
    }
}

// ---------------- K5: per-image sequential NMS (100 iters), register-resident ----------------
__global__ void __launch_bounds__(256) k_nms(const float* __restrict__ cscore,
                                             const float* __restrict__ cbox,
                                             const int*   __restrict__ clab,
                                             float* __restrict__ out){
    int b = blockIdx.x, tid = threadIdx.x;
    // candidate i = k*256 + tid, k in [0,8) -> covers 2048 >= NCAND (pads zeroed)
    float s[8], x0[8], y0[8], x1[8], y1[8];
    __shared__ float lcbox[2048][4];
    __shared__ int   llab[2048];
    __shared__ float rv[4]; __shared__ int ri[4];
    __shared__ float sbx[4];
    #pragma unroll
    for (int k=0;k<8;++k){
        int i = k*256 + tid;
        if (i < NCAND){
            int ci = b*NCAND + i;
            float4 bb = *(const float4*)(cbox + (size_t)ci*4);
            int lab = clab[ci];
            float sc = cscore[ci];
            lcbox[i][0]=bb.x; lcbox[i][1]=bb.y; lcbox[i][2]=bb.z; lcbox[i][3]=bb.w;
            llab[i] = lab;
            float lo = 1025.0f * (float)lab;     // (IMG+1)*label class-offset
            s[k]=sc; x0[k]=bb.x+lo; y0[k]=bb.y+lo; x1[k]=bb.z+lo; y1[k]=bb.w+lo;
        } else {
            lcbox[i][0]=0; lcbox[i][1]=0; lcbox[i][2]=0; lcbox[i][3]=0;
            llab[i]=0;
            s[k]=0.0f; x0[k]=0; y0[k]=0; x1[k]=0; y1[k]=0;
        }
    }
    __syncthreads();
    for (int it = 0; it < MAXPER; ++it){
        // local argmax over 8 regs (tie -> lower index)
        float v = s[0]; int bi = tid;
        #pragma unroll
        for (int k=1;k<8;++k){ if (s[k] > v){ v = s[k]; bi = k*256 + tid; } }
        // wave butterfly reduce
        #pragma unroll
        for (int off=32; off>=1; off>>=1){
            float ov = __shfl_xor(v, off);
            int   oi = __shfl_xor(bi, off);
            if (ov > v || (ov == v && oi < bi)){ v = ov; bi = oi; }
        }
        if ((tid & 63) == 0){ rv[tid>>6] = v; ri[tid>>6] = bi; }
        __syncthreads();                                  // A
        float vj = rv[0]; int j = ri[0];
        #pragma unroll
        for (int w=1; w<4; ++w){
            if (rv[w] > vj || (rv[w] == vj && ri[w] < j)){ vj = rv[w]; j = ri[w]; }
        }
        if (tid == (j & 255)){
            int k = j >> 8;
            sbx[0]=x0[k]; sbx[1]=y0[k]; sbx[2]=x1[k]; sbx[3]=y1[k];
        }
        if (tid == 0){
            bool valid = vj > 0.0f;
            float* det = out + ((size_t)b*MAXPER + it)*5;
            det[0] = valid ? lcbox[j][0] : 0.0f;
            det[1] = valid ? lcbox[j][1] : 0.0f;
            det[2] = valid ? lcbox[j][2] : 0.0f;
            det[3] = valid ? lcbox[j][3] : 0.0f;
            det[4] = valid ? vj : 0.0f;
            out[NB*MAXPER*5 + b*MAXPER + it] = valid ? (float)llab[j] : -1.0f;
        }
        __syncthreads();                                  // B
        float jx0=sbx[0], jy0=sbx[1], jx1=sbx[2], jy1=sbx[3];
        float a1 = (jx1-jx0)*(jy1-jy0);
        #pragma unroll
        for (int k=0;k<8;++k){
            float lt0 = fmaxf(jx0, x0[k]), lt1 = fmaxf(jy0, y0[k]);
            float rb0 = fminf(jx1, x1[k]), rb1 = fminf(jy1, y1[k]);
            float w = fmaxf(rb0-lt0, 0.0f), h = fmaxf(rb1-lt1, 0.0f);
            float inter = w*h;
            float a2 = (x1[k]-x0[k])*(y1[k]-y0[k]);
            float iou = inter / fmaxf(a1 + a2 - inter, 1e-6f);
            if (iou >= 0.5f) s[k] = 0.0f;
        }
    }
}

extern "C" void kernel_launch(void* const* d_in, const int* in_sizes, int n_in,
                              void* d_out, int out_size, void* d_ws, size_t ws_size,
                              hipStream_t stream){
    const float *c[5], *bx[5], *ct[5];
    for (int l=0;l<5;++l){
        c[l]  = (const float*)d_in[3*l+0];
        bx[l] = (const float*)d_in[3*l+1];
        ct[l] = (const float*)d_in[3*l+2];
    }
    const int* imsz = (const int*)d_in[15];
    // workspace layout (floats), ~20.2 MB total
    float* ws       = (float*)d_ws;
    float* maxscore = ws;                                   // 349,184
    int*   sel      = (int*)(ws + 349184);                  //  53,120
    float* boxes    = ws + 349184 + 53120;                  // 212,480 (16B-aligned)
    float* finals   = boxes + 212480;                       // 4,249,600
    float* cscore   = finals + 4249600;                     //  32,000
    float* cbox     = cscore + 32000;                       // 128,000 (16B-aligned)
    int*   clab     = (int*)(cbox + 128000);                //  32,000
    float* out = (float*)d_out;

    k_maxscore<<<dim3((NB*(NPTS/4) + 255)/256), dim3(256), 0, stream>>>(
        c[0],c[1],c[2],c[3],c[4], maxscore);
    k_select<<<dim3(NB*5), dim3(256), 0, stream>>>(maxscore, sel);
    size_t total = (size_t)NB*NSEL*NCLS;
    k_gather<<<dim3((unsigned)((total + 255)/256)), dim3(256), 0, stream>>>(
        c[0],c[1],c[2],c[3],c[4],
        bx[0],bx[1],bx[2],bx[3],bx[4],
        ct[0],ct[1],ct[2],ct[3],ct[4],
        imsz, sel, boxes, finals);
    k_top<<<dim3(NB), dim3(1024), 0, stream>>>(finals, boxes, cscore, cbox, clab);
    k_nms<<<dim3(NB), dim3(256), 0, stream>>>(cscore, cbox, clab, out);
}

// Round 7
// 607.412 us; speedup vs baseline: 2.0545x; 2.0545x over previous
//
// R7: resubmission of R5/R6 (infra failures: 2x GPU timeout, 1x container fail; never ran).
// Experiment under test: grid-parallel 2x8-bit radix select replacing the
// latency-bound 16-block k_top/k_select (R4 evidence: Occ 2.9%, VALU 2.3%, HBM 0.2%).
// Predicted: k_top 611us -> ~60us, total 1248 -> ~450-520us, absmax 0.0.
#include <hip/hip_runtime.h>
#include <cstdint>
#include <cstddef>

#define NCLS   80
#define NB     16
#define NPTS   21824      // 16384+4096+1024+256+64
#define NSEL   3320       // 1000+1000+1000+256+64
#define NTOT   (NSEL*NCLS) // 265600 per image
#define NCAND  2000
#define MAXPER 100
#define TCHUNK 66400      // NTOT/4
#define TIECAP 4096
#define TIECAP_SEL 4096

__device__ __forceinline__ float sigmoidf_(float x){ return 1.0f/(1.0f+expf(-x)); }
// monotone-increasing unsigned key for f32 (finite inputs)
__device__ __forceinline__ unsigned fkey(float f){
    unsigned u = __float_as_uint(f);
    return (u & 0x80000000u) ? ~u : (u | 0x80000000u);
}

// wave-aggregated histogram add: one LDS atomic per distinct bucket per wave
__device__ __forceinline__ void wave_hist_add(unsigned* hist, int bucket, bool active){
    unsigned long long rem = __ballot(active);
    int lane = threadIdx.x & 63;
    while (rem){
        int leader = __ffsll((long long)rem) - 1;
        int lb = __shfl(bucket, leader);
        unsigned long long match = __ballot(active && bucket == lb);
        if (lane == leader) atomicAdd(&hist[lb], (unsigned)__popcll(match));
        rem &= ~match;
    }
}

// ---------------- K1: per-point max class score (sigmoid of max logit), float4 ----------------
__global__ void k_maxscore(const float* __restrict__ c0, const float* __restrict__ c1,
                           const float* __restrict__ c2, const float* __restrict__ c3,
                           const float* __restrict__ c4, float* __restrict__ maxscore){
    const int GP = NPTS/4;
    int g = blockIdx.x*blockDim.x + threadIdx.x;
    if (g >= NB*GP) return;
    int b = g / GP, r = (g - b*GP)*4;
    const float* cls; int n, p;
    if      (r < 16384){ cls=c0; n=16384; p=r; }
    else if (r < 20480){ cls=c1; n=4096;  p=r-16384; }
    else if (r < 21504){ cls=c2; n=1024;  p=r-20480; }
    else if (r < 21760){ cls=c3; n=256;   p=r-21504; }
    else               { cls=c4; n=64;    p=r-21760; }
    const float* base = cls + (size_t)b*NCLS*n + p;
    float4 m = make_float4(-3.4e38f,-3.4e38f,-3.4e38f,-3.4e38f);
    #pragma unroll 8
    for (int c = 0; c < NCLS; ++c){
        const float4 v = *(const float4*)(base + (size_t)c*n);
        m.x = fmaxf(m.x, v.x); m.y = fmaxf(m.y, v.y);
        m.z = fmaxf(m.z, v.z); m.w = fmaxf(m.w, v.w);
    }
    float4 s = make_float4(sigmoidf_(m.x), sigmoidf_(m.y), sigmoidf_(m.z), sigmoidf_(m.w));
    *(float4*)(maxscore + (size_t)b*NPTS + r) = s;
}

// ---------------- K2: per-(image,level) top-k, in-block 2x8-bit radix + tie rank ----------------
__global__ void __launch_bounds__(1024) k_select(const float* __restrict__ maxscore,
                                                 int* __restrict__ sel){
    int blk = blockIdx.x; int b = blk/5, li = blk - 5*b;
    int n, k, poff, soff;
    if      (li==0){ n=16384; k=1000; poff=0;     soff=0;    }
    else if (li==1){ n=4096;  k=1000; poff=16384; soff=1000; }
    else if (li==2){ n=1024;  k=1000; poff=20480; soff=2000; }
    else if (li==3){ n=256;   k=256;  poff=21504; soff=3000; }
    else           { n=64;    k=64;   poff=21760; soff=3256; }
    const float* x = maxscore + b*NPTS + poff;
    int* out = sel + b*NSEL + soff;
    int tid = threadIdx.x, nt = blockDim.x;
    if (k == n){ for (int i=tid;i<n;i+=nt) out[i]=i; return; }

    __shared__ unsigned suf[256];
    __shared__ int sh_d, sh_s1, s_cnt, s_tc;
    __shared__ float tk[TIECAP_SEL];
    __shared__ int   ti[TIECAP_SEL];

    for (int i=tid;i<256;i+=nt) suf[i]=0u;
    if (tid==0){ s_cnt=0; s_tc=0; }
    __syncthreads();
    // pass A: top 8 bits
    for (int i0=0;i0<n;i0+=nt){
        int i=i0+tid; bool act=(i<n);
        int bkt = act ? (int)(fkey(x[i])>>24) : 0;
        wave_hist_add(suf, bkt, act);
    }
    __syncthreads();
    for (int o=1;o<256;o<<=1){
        unsigned v=(tid<256 && tid+o<256)?suf[tid+o]:0u; __syncthreads();
        if (tid<256) suf[tid]+=v; __syncthreads();
    }
    if (tid<256){
        unsigned s1=(tid<255)?suf[tid+1]:0u;
        if (suf[tid]>=(unsigned)k && s1<(unsigned)k){ sh_d=tid; sh_s1=(int)s1; }
    }
    __syncthreads();
    int T8 = sh_d, base8 = sh_s1, r8 = k - sh_s1;
    __syncthreads();
    for (int i=tid;i<256;i+=nt) suf[i]=0u;
    __syncthreads();
    // pass B: bits 16-23 among key8==T8
    for (int i0=0;i0<n;i0+=nt){
        int i=i0+tid; bool act=false; int bkt=0;
        if (i<n){ unsigned key=fkey(x[i]); act=((int)(key>>24)==T8); bkt=(int)((key>>16)&255u); }
        wave_hist_add(suf, bkt, act);
    }
    __syncthreads();
    for (int o=1;o<256;o<<=1){
        unsigned v=(tid<256 && tid+o<256)?suf[tid+o]:0u; __syncthreads();
        if (tid<256) suf[tid]+=v; __syncthreads();
    }
    if (tid<256){
        unsigned s1=(tid<255)?suf[tid+1]:0u;
        if (suf[tid]>=(unsigned)r8 && s1<(unsigned)r8){ sh_d=tid; sh_s1=(int)s1; }
    }
    __syncthreads();
    int T16 = (T8<<8) | sh_d;
    int base = base8 + sh_s1;
    int r = r8 - sh_s1;
    // compact: >T16 appended (set semantics), ==T16 collected for exact ranking
    for (int i=tid;i<n;i+=nt){
        int k16 = (int)(fkey(x[i])>>16);
        if (k16 > T16) out[atomicAdd(&s_cnt,1)] = i;
        else if (k16 == T16){
            int p = atomicAdd(&s_tc,1);
            if (p < TIECAP_SEL){ tk[p]=x[i]; ti[p]=i; }
        }
    }
    __syncthreads();
    int m = s_tc; if (m > TIECAP_SEL) m = TIECAP_SEL;
    for (int i=tid;i<m;i+=nt){
        unsigned ki = fkey(tk[i]); int ii = ti[i]; int rk = 0;
        for (int j=0;j<m;++j){
            unsigned kj = fkey(tk[j]);
            rk += (kj>ki || (kj==ki && ti[j]<ii)) ? 1 : 0;
        }
        if (rk < r) out[base+rk] = ii;   // lowest-index tie-break == lax.top_k
    }
}

// ---------------- K3: gather selected points, decode boxes, fused thresholded scores ----------------
__global__ void k_gather(const float* __restrict__ c0, const float* __restrict__ c1,
                         const float* __restrict__ c2, const float* __restrict__ c3,
                         const float* __restrict__ c4,
                         const float* __restrict__ b0, const float* __restrict__ b1,
                         const float* __restrict__ b2, const float* __restrict__ b3,
                         const float* __restrict__ b4,
                         const float* __restrict__ t0, const float* __restrict__ t1,
                         const float* __restrict__ t2, const float* __restrict__ t3,
                         const float* __restrict__ t4,
                         const int* __restrict__ imsz, const int* __restrict__ sel,
                         float* __restrict__ boxes, float* __restrict__ finals){
    size_t i = (size_t)blockIdx.x*blockDim.x + threadIdx.x;
    const size_t total = (size_t)NB*NTOT;
    if (i >= total) return;
    int b = (int)(i / NTOT);
    int r = (int)(i - (size_t)b*NTOT);
    int slot = r / NCLS, c = r - slot*NCLS;
    const float *cls, *bb, *ct; int n, hw, st;
    if      (slot < 1000){ cls=c0; bb=b0; ct=t0; n=16384; hw=128; st=8;   }
    else if (slot < 2000){ cls=c1; bb=b1; ct=t1; n=4096;  hw=64;  st=16;  }
    else if (slot < 3000){ cls=c2; bb=b2; ct=t2; n=1024;  hw=32;  st=32;  }
    else if (slot < 3256){ cls=c3; bb=b3; ct=t3; n=256;   hw=16;  st=64;  }
    else                 { cls=c4; bb=b4; ct=t4; n=64;    hw=8;   st=128; }
    int p = sel[b*NSEL + slot];
    float ctrn = sigmoidf_(ct[(size_t)b*n + p]);
    float sc = sigmoidf_(cls[((size_t)b*NCLS + c)*n + p]) * ctrn;
    finals[(size_t)b*NTOT + r] = (sc > 0.05f) ? sc : 0.0f;
    if (c == 0){
        const float* base = bb + (size_t)b*4*n;
        float d0 = base[p], d1 = base[n+p], d2 = base[2*n+p], d3 = base[3*n+p];
        int py = p / hw, px = p - py*hw;
        float mx = (float)(px*st + st/2), my = (float)(py*st + st/2);
        float w = (float)imsz[b*2+1], h = (float)imsz[b*2+0];
        float x1 = fminf(fmaxf(mx - d0, 0.0f), w);
        float y1 = fminf(fmaxf(my - d1, 0.0f), h);
        float x2 = fminf(fmaxf(mx + d2, 0.0f), w);
        float y2 = fminf(fmaxf(my + d3, 0.0f), h);
        float* bo = boxes + ((size_t)b*NSEL + slot)*4;
        bo[0]=x1; bo[1]=y1; bo[2]=x2; bo[3]=y2;
    }
}

// ---------------- K4: per-image top-2000, grid-parallel 2x8-bit radix ----------------
__global__ void k_zero(unsigned* __restrict__ ghA){
    int i = blockIdx.x*blockDim.x + threadIdx.x;
    if (i < NB*256) ghA[i] = 0u;
}

__global__ void __launch_bounds__(1024) k_topA(const float* __restrict__ finals,
                                               unsigned* __restrict__ ghA){
    int img = blockIdx.x >> 2, part = blockIdx.x & 3;
    const float* x = finals + (size_t)img*NTOT;
    __shared__ unsigned h[256];
    int tid = threadIdx.x, nt = blockDim.x;
    for (int i=tid;i<256;i+=nt) h[i]=0u;
    __syncthreads();
    int lo = part*TCHUNK, hi = lo + TCHUNK;
    for (int i0=lo;i0<hi;i0+=nt){
        int i = i0 + tid; bool act = (i < hi);
        int bkt = act ? (int)(fkey(x[i])>>24) : 0;
        wave_hist_add(h, bkt, act);
    }
    __syncthreads();
    for (int i=tid;i<256;i+=nt) if (h[i]) atomicAdd(&ghA[img*256+i], h[i]);
}

// prm per image: [0]=T8 [1]=r8 [2]=base8 [3]=T16 [4]=base [5]=r [6]=appcnt [7]=tiecnt
__global__ void k_threshA(const unsigned* __restrict__ ghA, unsigned* __restrict__ ghB,
                          int* __restrict__ prm){
    int img = blockIdx.x, tid = threadIdx.x;   // 256 threads
    __shared__ unsigned suf[256];
    suf[tid] = ghA[img*256+tid];
    ghB[img*256+tid] = 0u;
    __syncthreads();
    for (int o=1;o<256;o<<=1){
        unsigned v = (tid+o<256)?suf[tid+o]:0u; __syncthreads();
        suf[tid]+=v; __syncthreads();
    }
    unsigned s1 = (tid<255)?suf[tid+1]:0u;
    if (suf[tid] >= (unsigned)NCAND && s1 < (unsigned)NCAND){
        prm[img*8+0]=tid; prm[img*8+1]=NCAND-(int)s1; prm[img*8+2]=(int)s1;
    }
}

__global__ void __launch_bounds__(1024) k_topB(const float* __restrict__ finals,
                                               const int* __restrict__ prm,
                                               unsigned* __restrict__ ghB){
    int img = blockIdx.x >> 2, part = blockIdx.x & 3;
    const float* x = finals + (size_t)img*NTOT;
    int T8 = prm[img*8+0];
    __shared__ unsigned h[256];
    int tid = threadIdx.x, nt = blockDim.x;
    for (int i=tid;i<256;i+=nt) h[i]=0u;
    __syncthreads();
    int lo = part*TCHUNK, hi = lo + TCHUNK;
    for (int i0=lo;i0<hi;i0+=nt){
        int i = i0 + tid; bool act=false; int bkt=0;
        if (i < hi){ unsigned key=fkey(x[i]); act=((int)(key>>24)==T8); bkt=(int)((key>>16)&255u); }
        wave_hist_add(h, bkt, act);
    }
    __syncthreads();
    for (int i=tid;i<256;i+=nt) if (h[i]) atomicAdd(&ghB[img*256+i], h[i]);
}

__global__ void k_threshB(const unsigned* __restrict__ ghB, int* __restrict__ prm){
    int img = blockIdx.x, tid = threadIdx.x;   // 256 threads
    __shared__ unsigned suf[256];
    int T8 = prm[img*8+0], r8 = prm[img*8+1], base8 = prm[img*8+2];
    suf[tid] = ghB[img*256+tid];
    __syncthreads();
    for (int o=1;o<256;o<<=1){
        unsigned v = (tid+o<256)?suf[tid+o]:0u; __syncthreads();
        suf[tid]+=v; __syncthreads();
    }
    unsigned s1 = (tid<255)?suf[tid+1]:0u;
    if (suf[tid] >= (unsigned)r8 && s1 < (unsigned)r8){
        prm[img*8+3]=(T8<<8)|tid;
        prm[img*8+4]=base8+(int)s1;
        prm[img*8+5]=r8-(int)s1;
    }
    if (tid==0){ prm[img*8+6]=0; prm[img*8+7]=0; }
}

__global__ void __launch_bounds__(1024) k_compact(const float* __restrict__ finals,
                                                  const float* __restrict__ boxes,
                                                  int* __restrict__ prm,
                                                  float* __restrict__ cscore,
                                                  float* __restrict__ cbox,
                                                  int* __restrict__ clab,
                                                  float* __restrict__ tieS,
                                                  int* __restrict__ tieI){
    int img = blockIdx.x >> 2, part = blockIdx.x & 3;
    const float* x = finals + (size_t)img*NTOT;
    int T16 = prm[img*8+3];
    int* appc = &prm[img*8+6];
    int* tiec = &prm[img*8+7];
    int tid = threadIdx.x, nt = blockDim.x, lane = tid & 63;
    int lo = part*TCHUNK, hi = lo + TCHUNK;
    for (int i0=lo;i0<hi;i0+=nt){
        int i = i0 + tid;
        bool insel=false, intie=false;
        if (i < hi){
            int k16 = (int)(fkey(x[i])>>16);
            insel = (k16 > T16); intie = (k16 == T16);
        }
        // wave-aggregated append: 1 global atomic per wave
        unsigned long long mk = __ballot(insel);
        if (mk){
            int ldr = __ffsll((long long)mk)-1; int pb=0;
            if (lane==ldr) pb = atomicAdd(appc, __popcll(mk));
            pb = __shfl(pb, ldr);
            if (insel){
                int pos = pb + __popcll(mk & ((1ull<<lane)-1ull));
                int ci = img*NCAND + pos;
                int slot = i/NCLS, lab = i - slot*NCLS;
                cscore[ci] = x[i]; clab[ci] = lab;
                *(float4*)(cbox + (size_t)ci*4) = *(const float4*)(boxes + ((size_t)img*NSEL + slot)*4);
            }
        }
        unsigned long long mt = __ballot(intie);
        if (mt){
            int ldr = __ffsll((long long)mt)-1; int pb=0;
            if (lane==ldr) pb = atomicAdd(tiec, __popcll(mt));
            pb = __shfl(pb, ldr);
            if (intie){
                int p = pb + __popcll(mt & ((1ull<<lane)-1ull));
                if (p < TIECAP){ tieS[img*TIECAP+p] = x[i]; tieI[img*TIECAP+p] = i; }
            }
        }
    }
}

__global__ void __launch_bounds__(1024) k_ties(const int* __restrict__ prm,
                                               const float* __restrict__ tieS,
                                               const int* __restrict__ tieI,
                                               const float* __restrict__ boxes,
                                               float* __restrict__ cscore,
                                               float* __restrict__ cbox,
                                               int* __restrict__ clab){
    int img = blockIdx.x, tid = threadIdx.x, nt = blockDim.x;
    int base = prm[img*8+4], r = prm[img*8+5];
    int m = prm[img*8+7]; if (m > TIECAP) m = TIECAP;
    __shared__ float sk[TIECAP];
    __shared__ int   si[TIECAP];
    for (int i=tid;i<m;i+=nt){ sk[i]=tieS[img*TIECAP+i]; si[i]=tieI[img*TIECAP+i]; }
    __syncthreads();
    for (int i=tid;i<m;i+=nt){
        unsigned ki = fkey(sk[i]); int ii = si[i]; int rk = 0;
        for (int j=0;j<m;++j){
            unsigned kj = fkey(sk[j]);
            rk += (kj>ki || (kj==ki && si[j]<ii)) ? 1 : 0;
        }
        if (rk < r){
            int ci = img*NCAND + base + rk;
            int slot = ii/NCLS, lab = ii - slot*NCLS;
            cscore[ci] = sk[i]; clab[ci] = lab;
            *(float4*)(cbox + (size_t)ci*4) = *(const float4*)(boxes + ((size_t)img*NSEL + slot)*4);
        }
    }
}

// ---------------- K5: per-image sequential NMS (100 iters), register-resident ----------------
__global__ void __launch_bounds__(256) k_nms(const float* __restrict__ cscore,
                                             const float* __restrict__ cbox,
                                             const int*   __restrict__ clab,
                                             float* __restrict__ out){
    int b = blockIdx.x, tid = threadIdx.x;
    float s[8], x0[8], y0[8], x1[8], y1[8];
    __shared__ float lcbox[2048][4];
    __shared__ int   llab[2048];
    __shared__ float rv[4]; __shared__ int ri[4];
    __shared__ float sbx[4];
    #pragma unroll
    for (int k=0;k<8;++k){
        int i = k*256 + tid;
        if (i < NCAND){
            int ci = b*NCAND + i;
            float4 bb = *(const float4*)(cbox + (size_t)ci*4);
            int lab = clab[ci];
            float sc = cscore[ci];
            lcbox[i][0]=bb.x; lcbox[i][1]=bb.y; lcbox[i][2]=bb.z; lcbox[i][3]=bb.w;
            llab[i] = lab;
            float lo = 1025.0f * (float)lab;
            s[k]=sc; x0[k]=bb.x+lo; y0[k]=bb.y+lo; x1[k]=bb.z+lo; y1[k]=bb.w+lo;
        } else {
            lcbox[i][0]=0; lcbox[i][1]=0; lcbox[i][2]=0; lcbox[i][3]=0;
            llab[i]=0;
            s[k]=0.0f; x0[k]=0; y0[k]=0; x1[k]=0; y1[k]=0;
        }
    }
    __syncthreads();
    for (int it = 0; it < MAXPER; ++it){
        float v = s[0]; int bi = tid;
        #pragma unroll
        for (int k=1;k<8;++k){ if (s[k] > v){ v = s[k]; bi = k*256 + tid; } }
        #pragma unroll
        for (int off=32; off>=1; off>>=1){
            float ov = __shfl_xor(v, off);
            int   oi = __shfl_xor(bi, off);
            if (ov > v || (ov == v && oi < bi)){ v = ov; bi = oi; }
        }
        if ((tid & 63) == 0){ rv[tid>>6] = v; ri[tid>>6] = bi; }
        __syncthreads();
        float vj = rv[0]; int j = ri[0];
        #pragma unroll
        for (int w=1; w<4; ++w){
            if (rv[w] > vj || (rv[w] == vj && ri[w] < j)){ vj = rv[w]; j = ri[w]; }
        }
        if (tid == (j & 255)){
            int k = j >> 8;
            sbx[0]=x0[k]; sbx[1]=y0[k]; sbx[2]=x1[k]; sbx[3]=y1[k];
        }
        if (tid == 0){
            bool valid = vj > 0.0f;
            float* det = out + ((size_t)b*MAXPER + it)*5;
            det[0] = valid ? lcbox[j][0] : 0.0f;
            det[1] = valid ? lcbox[j][1] : 0.0f;
            det[2] = valid ? lcbox[j][2] : 0.0f;
            det[3] = valid ? lcbox[j][3] : 0.0f;
            det[4] = valid ? vj : 0.0f;
            out[NB*MAXPER*5 + b*MAXPER + it] = valid ? (float)llab[j] : -1.0f;
        }
        __syncthreads();
        float jx0=sbx[0], jy0=sbx[1], jx1=sbx[2], jy1=sbx[3];
        float a1 = (jx1-jx0)*(jy1-jy0);
        #pragma unroll
        for (int k=0;k<8;++k){
            float lt0 = fmaxf(jx0, x0[k]), lt1 = fmaxf(jy0, y0[k]);
            float rb0 = fminf(jx1, x1[k]), rb1 = fminf(jy1, y1[k]);
            float w = fmaxf(rb0-lt0, 0.0f), h = fmaxf(rb1-lt1, 0.0f);
            float inter = w*h;
            float a2 = (x1[k]-x0[k])*(y1[k]-y0[k]);
            float iou = inter / fmaxf(a1 + a2 - inter, 1e-6f);
            if (iou >= 0.5f) s[k] = 0.0f;
        }
    }
}

extern "C" void kernel_launch(void* const* d_in, const int* in_sizes, int n_in,
                              void* d_out, int out_size, void* d_ws, size_t ws_size,
                              hipStream_t stream){
    const float *c[5], *bx[5], *ct[5];
    for (int l=0;l<5;++l){
        c[l]  = (const float*)d_in[3*l+0];
        bx[l] = (const float*)d_in[3*l+1];
        ct[l] = (const float*)d_in[3*l+2];
    }
    const int* imsz = (const int*)d_in[15];
    // workspace layout (float words), ~20.8 MB total
    float* ws        = (float*)d_ws;
    float*    maxscore = ws;                           // 349,184
    int*      sel      = (int*)(ws + 349184);          //  53,120 -> 402,304
    float*    boxes    = ws + 402304;                  // 212,480 -> 614,784
    float*    finals   = ws + 614784;                  // 4,249,600 -> 4,864,384
    float*    cscore   = ws + 4864384;                 //  32,000 -> 4,896,384
    float*    cbox     = ws + 4896384;                 // 128,000 -> 5,024,384
    int*      clab     = (int*)(ws + 5024384);         //  32,000 -> 5,056,384
    unsigned* ghA      = (unsigned*)(ws + 5056384);    //   4,096 -> 5,060,480
    unsigned* ghB      = (unsigned*)(ws + 5060480);    //   4,096 -> 5,064,576
    int*      prm      = (int*)(ws + 5064576);         //     128 -> 5,064,704
    float*    tieS     = ws + 5064704;                 //  65,536 -> 5,130,240
    int*      tieI     = (int*)(ws + 5130240);         //  65,536 -> 5,195,776
    float* out = (float*)d_out;

    k_zero<<<dim3(16), dim3(256), 0, stream>>>(ghA);
    k_maxscore<<<dim3((NB*(NPTS/4) + 255)/256), dim3(256), 0, stream>>>(
        c[0],c[1],c[2],c[3],c[4], maxscore);
    k_select<<<dim3(NB*5), dim3(1024), 0, stream>>>(maxscore, sel);
    size_t total = (size_t)NB*NTOT;
    k_gather<<<dim3((unsigned)((total + 255)/256)), dim3(256), 0, stream>>>(
        c[0],c[1],c[2],c[3],c[4],
        bx[0],bx[1],bx[2],bx[3],bx[4],
        ct[0],ct[1],ct[2],ct[3],ct[4],
        imsz, sel, boxes, finals);
    k_topA<<<dim3(NB*4), dim3(1024), 0, stream>>>(finals, ghA);
    k_threshA<<<dim3(NB), dim3(256), 0, stream>>>(ghA, ghB, prm);
    k_topB<<<dim3(NB*4), dim3(1024), 0, stream>>>(finals, prm, ghB);
    k_threshB<<<dim3(NB), dim3(256), 0, stream>>>(ghB, prm);
    k_compact<<<dim3(NB*4), dim3(1024), 0, stream>>>(finals, boxes, prm, cscore, cbox, clab, tieS, tieI);
    k_ties<<<dim3(NB), dim3(1024), 0, stream>>>(prm, tieS, tieI, boxes, cscore, cbox, clab);
    k_nms<<<dim3(NB), dim3(256), 0, stream>>>(cscore, cbox, clab, out);
}

// Round 9
// 589.488 us; speedup vs baseline: 2.1170x; 1.0304x over previous
//
// R9: resubmission of R8 (GPU acquisition timeout; never ran).
// Experiment under test: k_nms v2 single-barrier iteration (packed u64 LDS
// atomicMax argmax, triple-buffered slots, boxes in regs+LDS).
// R7 evidence: k_nms 156us @ Occ 0.72%, VALU 1.9% (serial chain).
// Predicted: k_nms -> ~50us, total 607 -> ~500us, absmax 0.0.
#include <hip/hip_runtime.h>
#include <cstdint>
#include <cstddef>

#define NCLS   80
#define NB     16
#define NPTS   21824      // 16384+4096+1024+256+64
#define NSEL   3320       // 1000+1000+1000+256+64
#define NTOT   (NSEL*NCLS) // 265600 per image
#define NCAND  2000
#define MAXPER 100
#define TCHUNK 66400      // NTOT/4
#define TIECAP 4096
#define TIECAP_SEL 4096

__device__ __forceinline__ float sigmoidf_(float x){ return 1.0f/(1.0f+expf(-x)); }
// monotone-increasing unsigned key for f32 (finite inputs)
__device__ __forceinline__ unsigned fkey(float f){
    unsigned u = __float_as_uint(f);
    return (u & 0x80000000u) ? ~u : (u | 0x80000000u);
}

// wave-aggregated histogram add: one LDS atomic per distinct bucket per wave
__device__ __forceinline__ void wave_hist_add(unsigned* hist, int bucket, bool active){
    unsigned long long rem = __ballot(active);
    int lane = threadIdx.x & 63;
    while (rem){
        int leader = __ffsll((long long)rem) - 1;
        int lb = __shfl(bucket, leader);
        unsigned long long match = __ballot(active && bucket == lb);
        if (lane == leader) atomicAdd(&hist[lb], (unsigned)__popcll(match));
        rem &= ~match;
    }
}

// ---------------- K1: per-point max class score (sigmoid of max logit), float4 ----------------
__global__ void k_maxscore(const float* __restrict__ c0, const float* __restrict__ c1,
                           const float* __restrict__ c2, const float* __restrict__ c3,
                           const float* __restrict__ c4, float* __restrict__ maxscore){
    const int GP = NPTS/4;
    int g = blockIdx.x*blockDim.x + threadIdx.x;
    if (g >= NB*GP) return;
    int b = g / GP, r = (g - b*GP)*4;
    const float* cls; int n, p;
    if      (r < 16384){ cls=c0; n=16384; p=r; }
    else if (r < 20480){ cls=c1; n=4096;  p=r-16384; }
    else if (r < 21504){ cls=c2; n=1024;  p=r-20480; }
    else if (r < 21760){ cls=c3; n=256;   p=r-21504; }
    else               { cls=c4; n=64;    p=r-21760; }
    const float* base = cls + (size_t)b*NCLS*n + p;
    float4 m = make_float4(-3.4e38f,-3.4e38f,-3.4e38f,-3.4e38f);
    #pragma unroll 8
    for (int c = 0; c < NCLS; ++c){
        const float4 v = *(const float4*)(base + (size_t)c*n);
        m.x = fmaxf(m.x, v.x); m.y = fmaxf(m.y, v.y);
        m.z = fmaxf(m.z, v.z); m.w = fmaxf(m.w, v.w);
    }
    float4 s = make_float4(sigmoidf_(m.x), sigmoidf_(m.y), sigmoidf_(m.z), sigmoidf_(m.w));
    *(float4*)(maxscore + (size_t)b*NPTS + r) = s;
}

// ---------------- K2: per-(image,level) top-k, in-block 2x8-bit radix + tie rank ----------------
__global__ void __launch_bounds__(1024) k_select(const float* __restrict__ maxscore,
                                                 int* __restrict__ sel){
    int blk = blockIdx.x; int b = blk/5, li = blk - 5*b;
    int n, k, poff, soff;
    if      (li==0){ n=16384; k=1000; poff=0;     soff=0;    }
    else if (li==1){ n=4096;  k=1000; poff=16384; soff=1000; }
    else if (li==2){ n=1024;  k=1000; poff=20480; soff=2000; }
    else if (li==3){ n=256;   k=256;  poff=21504; soff=3000; }
    else           { n=64;    k=64;   poff=21760; soff=3256; }
    const float* x = maxscore + b*NPTS + poff;
    int* out = sel + b*NSEL + soff;
    int tid = threadIdx.x, nt = blockDim.x;
    if (k == n){ for (int i=tid;i<n;i+=nt) out[i]=i; return; }

    __shared__ unsigned suf[256];
    __shared__ int sh_d, sh_s1, s_cnt, s_tc;
    __shared__ float tk[TIECAP_SEL];
    __shared__ int   ti[TIECAP_SEL];

    for (int i=tid;i<256;i+=nt) suf[i]=0u;
    if (tid==0){ s_cnt=0; s_tc=0; }
    __syncthreads();
    // pass A: top 8 bits
    for (int i0=0;i0<n;i0+=nt){
        int i=i0+tid; bool act=(i<n);
        int bkt = act ? (int)(fkey(x[i])>>24) : 0;
        wave_hist_add(suf, bkt, act);
    }
    __syncthreads();
    for (int o=1;o<256;o<<=1){
        unsigned v=(tid<256 && tid+o<256)?suf[tid+o]:0u; __syncthreads();
        if (tid<256) suf[tid]+=v; __syncthreads();
    }
    if (tid<256){
        unsigned s1=(tid<255)?suf[tid+1]:0u;
        if (suf[tid]>=(unsigned)k && s1<(unsigned)k){ sh_d=tid; sh_s1=(int)s1; }
    }
    __syncthreads();
    int T8 = sh_d, base8 = sh_s1, r8 = k - sh_s1;
    __syncthreads();
    for (int i=tid;i<256;i+=nt) suf[i]=0u;
    __syncthreads();
    // pass B: bits 16-23 among key8==T8
    for (int i0=0;i0<n;i0+=nt){
        int i=i0+tid; bool act=false; int bkt=0;
        if (i<n){ unsigned key=fkey(x[i]); act=((int)(key>>24)==T8); bkt=(int)((key>>16)&255u); }
        wave_hist_add(suf, bkt, act);
    }
    __syncthreads();
    for (int o=1;o<256;o<<=1){
        unsigned v=(tid<256 && tid+o<256)?suf[tid+o]:0u; __syncthreads();
        if (tid<256) suf[tid]+=v; __syncthreads();
    }
    if (tid<256){
        unsigned s1=(tid<255)?suf[tid+1]:0u;
        if (suf[tid]>=(unsigned)r8 && s1<(unsigned)r8){ sh_d=tid; sh_s1=(int)s1; }
    }
    __syncthreads();
    int T16 = (T8<<8) | sh_d;
    int base = base8 + sh_s1;
    int r = r8 - sh_s1;
    // compact: >T16 appended (set semantics), ==T16 collected for exact ranking
    for (int i=tid;i<n;i+=nt){
        int k16 = (int)(fkey(x[i])>>16);
        if (k16 > T16) out[atomicAdd(&s_cnt,1)] = i;
        else if (k16 == T16){
            int p = atomicAdd(&s_tc,1);
            if (p < TIECAP_SEL){ tk[p]=x[i]; ti[p]=i; }
        }
    }
    __syncthreads();
    int m = s_tc; if (m > TIECAP_SEL) m = TIECAP_SEL;
    for (int i=tid;i<m;i+=nt){
        unsigned ki = fkey(tk[i]); int ii = ti[i]; int rk = 0;
        for (int j=0;j<m;++j){
            unsigned kj = fkey(tk[j]);
            rk += (kj>ki || (kj==ki && ti[j]<ii)) ? 1 : 0;
        }
        if (rk < r) out[base+rk] = ii;   // lowest-index tie-break == lax.top_k
    }
}

// ---------------- K3: gather selected points, decode boxes, fused thresholded scores ----------------
__global__ void k_gather(const float* __restrict__ c0, const float* __restrict__ c1,
                         const float* __restrict__ c2, const float* __restrict__ c3,
                         const float* __restrict__ c4,
                         const float* __restrict__ b0, const float* __restrict__ b1,
                         const float* __restrict__ b2, const float* __restrict__ b3,
                         const float* __restrict__ b4,
                         const float* __restrict__ t0, const float* __restrict__ t1,
                         const float* __restrict__ t2, const float* __restrict__ t3,
                         const float* __restrict__ t4,
                         const int* __restrict__ imsz, const int* __restrict__ sel,
                         float* __restrict__ boxes, float* __restrict__ finals){
    size_t i = (size_t)blockIdx.x*blockDim.x + threadIdx.x;
    const size_t total = (size_t)NB*NTOT;
    if (i >= total) return;
    int b = (int)(i / NTOT);
    int r = (int)(i - (size_t)b*NTOT);
    int slot = r / NCLS, c = r - slot*NCLS;
    const float *cls, *bb, *ct; int n, hw, st;
    if      (slot < 1000){ cls=c0; bb=b0; ct=t0; n=16384; hw=128; st=8;   }
    else if (slot < 2000){ cls=c1; bb=b1; ct=t1; n=4096;  hw=64;  st=16;  }
    else if (slot < 3000){ cls=c2; bb=b2; ct=t2; n=1024;  hw=32;  st=32;  }
    else if (slot < 3256){ cls=c3; bb=b3; ct=t3; n=256;   hw=16;  st=64;  }
    else                 { cls=c4; bb=b4; ct=t4; n=64;    hw=8;   st=128; }
    int p = sel[b*NSEL + slot];
    float ctrn = sigmoidf_(ct[(size_t)b*n + p]);
    float sc = sigmoidf_(cls[((size_t)b*NCLS + c)*n + p]) * ctrn;
    finals[(size_t)b*NTOT + r] = (sc > 0.05f) ? sc : 0.0f;
    if (c == 0){
        const float* base = bb + (size_t)b*4*n;
        float d0 = base[p], d1 = base[n+p], d2 = base[2*n+p], d3 = base[3*n+p];
        int py = p / hw, px = p - py*hw;
        float mx = (float)(px*st + st/2), my = (float)(py*st + st/2);
        float w = (float)imsz[b*2+1], h = (float)imsz[b*2+0];
        float x1 = fminf(fmaxf(mx - d0, 0.0f), w);
        float y1 = fminf(fmaxf(my - d1, 0.0f), h);
        float x2 = fminf(fmaxf(mx + d2, 0.0f), w);
        float y2 = fminf(fmaxf(my + d3, 0.0f), h);
        float* bo = boxes + ((size_t)b*NSEL + slot)*4;
        bo[0]=x1; bo[1]=y1; bo[2]=x2; bo[3]=y2;
    }
}

// ---------------- K4: per-image top-2000, grid-parallel 2x8-bit radix ----------------
__global__ void k_zero(unsigned* __restrict__ ghA){
    int i = blockIdx.x*blockDim.x + threadIdx.x;
    if (i < NB*256) ghA[i] = 0u;
}

__global__ void __launch_bounds__(1024) k_topA(const float* __restrict__ finals,
                                               unsigned* __restrict__ ghA){
    int img = blockIdx.x >> 2, part = blockIdx.x & 3;
    const float* x = finals + (size_t)img*NTOT;
    __shared__ unsigned h[256];
    int tid = threadIdx.x, nt = blockDim.x;
    for (int i=tid;i<256;i+=nt) h[i]=0u;
    __syncthreads();
    int lo = part*TCHUNK, hi = lo + TCHUNK;
    for (int i0=lo;i0<hi;i0+=nt){
        int i = i0 + tid; bool act = (i < hi);
        int bkt = act ? (int)(fkey(x[i])>>24) : 0;
        wave_hist_add(h, bkt, act);
    }
    __syncthreads();
    for (int i=tid;i<256;i+=nt) if (h[i]) atomicAdd(&ghA[img*256+i], h[i]);
}

// prm per image: [0]=T8 [1]=r8 [2]=base8 [3]=T16 [4]=base [5]=r [6]=appcnt [7]=tiecnt
__global__ void k_threshA(const unsigned* __restrict__ ghA, unsigned* __restrict__ ghB,
                          int* __restrict__ prm){
    int img = blockIdx.x, tid = threadIdx.x;   // 256 threads
    __shared__ unsigned suf[256];
    suf[tid] = ghA[img*256+tid];
    ghB[img*256+tid] = 0u;
    __syncthreads();
    for (int o=1;o<256;o<<=1){
        unsigned v = (tid+o<256)?suf[tid+o]:0u; __syncthreads();
        suf[tid]+=v; __syncthreads();
    }
    unsigned s1 = (tid<255)?suf[tid+1]:0u;
    if (suf[tid] >= (unsigned)NCAND && s1 < (unsigned)NCAND){
        prm[img*8+0]=tid; prm[img*8+1]=NCAND-(int)s1; prm[img*8+2]=(int)s1;
    }
}

__global__ void __launch_bounds__(1024) k_topB(const float* __restrict__ finals,
                                               const int* __restrict__ prm,
                                               unsigned* __restrict__ ghB){
    int img = blockIdx.x >> 2, part = blockIdx.x & 3;
    const float* x = finals + (size_t)img*NTOT;
    int T8 = prm[img*8+0];
    __shared__ unsigned h[256];
    int tid = threadIdx.x, nt = blockDim.x;
    for (int i=tid;i<256;i+=nt) h[i]=0u;
    __syncthreads();
    int lo = part*TCHUNK, hi = lo + TCHUNK;
    for (int i0=lo;i0<hi;i0+=nt){
        int i = i0 + tid; bool act=false; int bkt=0;
        if (i < hi){ unsigned key=fkey(x[i]); act=((int)(key>>24)==T8); bkt=(int)((key>>16)&255u); }
        wave_hist_add(h, bkt, act);
    }
    __syncthreads();
    for (int i=tid;i<256;i+=nt) if (h[i]) atomicAdd(&ghB[img*256+i], h[i]);
}

__global__ void k_threshB(const unsigned* __restrict__ ghB, int* __restrict__ prm){
    int img = blockIdx.x, tid = threadIdx.x;   // 256 threads
    __shared__ unsigned suf[256];
    int T8 = prm[img*8+0], r8 = prm[img*8+1], base8 = prm[img*8+2];
    suf[tid] = ghB[img*256+tid];
    __syncthreads();
    for (int o=1;o<256;o<<=1){
        unsigned v = (tid+o<256)?suf[tid+o]:0u; __syncthreads();
        suf[tid]+=v; __syncthreads();
    }
    unsigned s1 = (tid<255)?suf[tid+1]:0u;
    if (suf[tid] >= (unsigned)r8 && s1 < (unsigned)r8){
        prm[img*8+3]=(T8<<8)|tid;
        prm[img*8+4]=base8+(int)s1;
        prm[img*8+5]=r8-(int)s1;
    }
    if (tid==0){ prm[img*8+6]=0; prm[img*8+7]=0; }
}

__global__ void __launch_bounds__(1024) k_compact(const float* __restrict__ finals,
                                                  const float* __restrict__ boxes,
                                                  int* __restrict__ prm,
                                                  float* __restrict__ cscore,
                                                  float* __restrict__ cbox,
                                                  int* __restrict__ clab,
                                                  float* __restrict__ tieS,
                                                  int* __restrict__ tieI){
    int img = blockIdx.x >> 2, part = blockIdx.x & 3;
    const float* x = finals + (size_t)img*NTOT;
    int T16 = prm[img*8+3];
    int* appc = &prm[img*8+6];
    int* tiec = &prm[img*8+7];
    int tid = threadIdx.x, nt = blockDim.x, lane = tid & 63;
    int lo = part*TCHUNK, hi = lo + TCHUNK;
    for (int i0=lo;i0<hi;i0+=nt){
        int i = i0 + tid;
        bool insel=false, intie=false;
        if (i < hi){
            int k16 = (int)(fkey(x[i])>>16);
            insel = (k16 > T16); intie = (k16 == T16);
        }
        // wave-aggregated append: 1 global atomic per wave
        unsigned long long mk = __ballot(insel);
        if (mk){
            int ldr = __ffsll((long long)mk)-1; int pb=0;
            if (lane==ldr) pb = atomicAdd(appc, __popcll(mk));
            pb = __shfl(pb, ldr);
            if (insel){
                int pos = pb + __popcll(mk & ((1ull<<lane)-1ull));
                int ci = img*NCAND + pos;
                int slot = i/NCLS, lab = i - slot*NCLS;
                cscore[ci] = x[i]; clab[ci] = lab;
                *(float4*)(cbox + (size_t)ci*4) = *(const float4*)(boxes + ((size_t)img*NSEL + slot)*4);
            }
        }
        unsigned long long mt = __ballot(intie);
        if (mt){
            int ldr = __ffsll((long long)mt)-1; int pb=0;
            if (lane==ldr) pb = atomicAdd(tiec, __popcll(mt));
            pb = __shfl(pb, ldr);
            if (intie){
                int p = pb + __popcll(mt & ((1ull<<lane)-1ull));
                if (p < TIECAP){ tieS[img*TIECAP+p] = x[i]; tieI[img*TIECAP+p] = i; }
            }
        }
    }
}

__global__ void __launch_bounds__(1024) k_ties(const int* __restrict__ prm,
                                               const float* __restrict__ tieS,
                                               const int* __restrict__ tieI,
                                               const float* __restrict__ boxes,
                                               float* __restrict__ cscore,
                                               float* __restrict__ cbox,
                                               int* __restrict__ clab){
    int img = blockIdx.x, tid = threadIdx.x, nt = blockDim.x;
    int base = prm[img*8+4], r = prm[img*8+5];
    int m = prm[img*8+7]; if (m > TIECAP) m = TIECAP;
    __shared__ float sk[TIECAP];
    __shared__ int   si[TIECAP];
    for (int i=tid;i<m;i+=nt){ sk[i]=tieS[img*TIECAP+i]; si[i]=tieI[img*TIECAP+i]; }
    __syncthreads();
    for (int i=tid;i<m;i+=nt){
        unsigned ki = fkey(sk[i]); int ii = si[i]; int rk = 0;
        for (int j=0;j<m;++j){
            unsigned kj = fkey(sk[j]);
            rk += (kj>ki || (kj==ki && si[j]<ii)) ? 1 : 0;
        }
        if (rk < r){
            int ci = img*NCAND + base + rk;
            int slot = ii/NCLS, lab = ii - slot*NCLS;
            cscore[ci] = sk[i]; clab[ci] = lab;
            *(float4*)(cbox + (size_t)ci*4) = *(const float4*)(boxes + ((size_t)img*NSEL + slot)*4);
        }
    }
}

// ---------------- K5: per-image sequential NMS, single-barrier iteration ----------------
// Block argmax via packed u64 LDS atomicMax: key = fkey(score)<<32 | ~index
// (~index -> ties resolve to LOWEST index, matching jnp.argmax). Triple-buffered
// slots: slot p is reset at iter it+1 (after barrier it+1), next atomicMax on it
// at iter it+3 (after barrier it+2) -> race-free with ONE barrier per iteration.
__global__ void __launch_bounds__(256) k_nms(const float* __restrict__ cscore,
                                             const float* __restrict__ cbox,
                                             const int*   __restrict__ clab,
                                             float* __restrict__ out){
    int b = blockIdx.x, tid = threadIdx.x;
    float s[8], x0[8], y0[8], x1[8], y1[8], a2[8];
    __shared__ float obx[2048][4];     // offset boxes (broadcast source)
    __shared__ float lcbox[2048][4];   // raw boxes (det output)
    __shared__ int   llab[2048];
    __shared__ unsigned long long pslot[3];
    #pragma unroll
    for (int k=0;k<8;++k){
        int i = k*256 + tid;
        if (i < NCAND){
            int ci = b*NCAND + i;
            float4 bb = *(const float4*)(cbox + (size_t)ci*4);
            int lab = clab[ci];
            s[k] = cscore[ci];
            lcbox[i][0]=bb.x; lcbox[i][1]=bb.y; lcbox[i][2]=bb.z; lcbox[i][3]=bb.w;
            llab[i] = lab;
            float lo = 1025.0f * (float)lab;   // (IMG+1)*label class-offset
            float ox0=bb.x+lo, oy0=bb.y+lo, ox1=bb.z+lo, oy1=bb.w+lo;
            obx[i][0]=ox0; obx[i][1]=oy0; obx[i][2]=ox1; obx[i][3]=oy1;
            x0[k]=ox0; y0[k]=oy0; x1[k]=ox1; y1[k]=oy1;
            a2[k]=(ox1-ox0)*(oy1-oy0);
        } else {
            s[k]=0.0f; x0[k]=0.0f; y0[k]=0.0f; x1[k]=0.0f; y1[k]=0.0f; a2[k]=0.0f;
            obx[i][0]=0; obx[i][1]=0; obx[i][2]=0; obx[i][3]=0;
            lcbox[i][0]=0; lcbox[i][1]=0; lcbox[i][2]=0; lcbox[i][3]=0;
            llab[i]=0;
        }
    }
    if (tid < 3) pslot[tid] = 0ull;
    __syncthreads();
    int p = 0;
    for (int it = 0; it < MAXPER; ++it){
        // local argmax over 8 regs (tie -> lower index)
        float v = s[0]; int bi = tid;
        #pragma unroll
        for (int k=1;k<8;++k){ if (s[k] > v){ v = s[k]; bi = k*256 + tid; } }
        // wave butterfly
        #pragma unroll
        for (int off=32; off>=1; off>>=1){
            float ov = __shfl_xor(v, off);
            int   oi = __shfl_xor(bi, off);
            if (ov > v || (ov == v && oi < bi)){ v = ov; bi = oi; }
        }
        if ((tid & 63) == 0)
            atomicMax(&pslot[p], ((unsigned long long)fkey(v) << 32) | (unsigned)~bi);
        __syncthreads();   // the ONLY barrier per iteration
        unsigned long long pk = pslot[p];
        int j = (int)(~(unsigned)pk);
        float vj = __uint_as_float(((unsigned)(pk >> 32)) & 0x7FFFFFFFu); // scores >= 0
        float jx0 = obx[j][0], jy0 = obx[j][1], jx1 = obx[j][2], jy1 = obx[j][3];
        if (tid == 0){
            bool valid = vj > 0.0f;
            float* det = out + ((size_t)b*MAXPER + it)*5;
            det[0] = valid ? lcbox[j][0] : 0.0f;
            det[1] = valid ? lcbox[j][1] : 0.0f;
            det[2] = valid ? lcbox[j][2] : 0.0f;
            det[3] = valid ? lcbox[j][3] : 0.0f;
            det[4] = valid ? vj : 0.0f;
            out[NB*MAXPER*5 + b*MAXPER + it] = valid ? (float)llab[j] : -1.0f;
            int q = p + 2; if (q >= 3) q -= 3;
            pslot[q] = 0ull;   // for iter it+2; barrier of it+1 orders vs its use
        }
        float a1 = (jx1-jx0)*(jy1-jy0);
        #pragma unroll
        for (int k=0;k<8;++k){
            float lt0 = fmaxf(jx0, x0[k]), lt1 = fmaxf(jy0, y0[k]);
            float rb0 = fminf(jx1, x1[k]), rb1 = fminf(jy1, y1[k]);
            float w = fmaxf(rb0-lt0, 0.0f), h = fmaxf(rb1-lt1, 0.0f);
            float inter = w*h;
            float iou = inter / fmaxf(a1 + a2[k] - inter, 1e-6f);
            if (iou >= 0.5f) s[k] = 0.0f;
        }
        ++p; if (p == 3) p = 0;
    }
}

extern "C" void kernel_launch(void* const* d_in, const int* in_sizes, int n_in,
                              void* d_out, int out_size, void* d_ws, size_t ws_size,
                              hipStream_t stream){
    const float *c[5], *bx[5], *ct[5];
    for (int l=0;l<5;++l){
        c[l]  = (const float*)d_in[3*l+0];
        bx[l] = (const float*)d_in[3*l+1];
        ct[l] = (const float*)d_in[3*l+2];
    }
    const int* imsz = (const int*)d_in[15];
    // workspace layout (float words), ~20.8 MB total
    float* ws        = (float*)d_ws;
    float*    maxscore = ws;                           // 349,184
    int*      sel      = (int*)(ws + 349184);          //  53,120 -> 402,304
    float*    boxes    = ws + 402304;                  // 212,480 -> 614,784
    float*    finals   = ws + 614784;                  // 4,249,600 -> 4,864,384
    float*    cscore   = ws + 4864384;                 //  32,000 -> 4,896,384
    float*    cbox     = ws + 4896384;                 // 128,000 -> 5,024,384
    int*      clab     = (int*)(ws + 5024384);         //  32,000 -> 5,056,384
    unsigned* ghA      = (unsigned*)(ws + 5056384);    //   4,096 -> 5,060,480
    unsigned* ghB      = (unsigned*)(ws + 5060480);    //   4,096 -> 5,064,576
    int*      prm      = (int*)(ws + 5064576);         //     128 -> 5,064,704
    float*    tieS     = ws + 5064704;                 //  65,536 -> 5,130,240
    int*      tieI     = (int*)(ws + 5130240);         //  65,536 -> 5,195,776
    float* out = (float*)d_out;

    k_zero<<<dim3(16), dim3(256), 0, stream>>>(ghA);
    k_maxscore<<<dim3((NB*(NPTS/4) + 255)/256), dim3(256), 0, stream>>>(
        c[0],c[1],c[2],c[3],c[4], maxscore);
    k_select<<<dim3(NB*5), dim3(1024), 0, stream>>>(maxscore, sel);
    size_t total = (size_t)NB*NTOT;
    k_gather<<<dim3((unsigned)((total + 255)/256)), dim3(256), 0, stream>>>(
        c[0],c[1],c[2],c[3],c[4],
        bx[0],bx[1],bx[2],bx[3],bx[4],
        ct[0],ct[1],ct[2],ct[3],ct[4],
        imsz, sel, boxes, finals);
    k_topA<<<dim3(NB*4), dim3(1024), 0, stream>>>(finals, ghA);
    k_threshA<<<dim3(NB), dim3(256), 0, stream>>>(ghA, ghB, prm);
    k_topB<<<dim3(NB*4), dim3(1024), 0, stream>>>(finals, prm, ghB);
    k_threshB<<<dim3(NB), dim3(256), 0, stream>>>(ghB, prm);
    k_compact<<<dim3(NB*4), dim3(1024), 0, stream>>>(finals, boxes, prm, cscore, cbox, clab, tieS, tieI);
    k_ties<<<dim3(NB), dim3(1024), 0, stream>>>(prm, tieS, tieI, boxes, cscore, cbox, clab);
    k_nms<<<dim3(NB), dim3(256), 0, stream>>>(cscore, cbox, clab, out);
}